// Round 1
// 472.125 us; speedup vs baseline: 1.0018x; 1.0018x over previous
//
#include <hip/hip_runtime.h>
#include <hip/hip_fp16.h>

typedef float f4v __attribute__((ext_vector_type(4)));
typedef _Float16 h4 __attribute__((ext_vector_type(4)));
typedef _Float16 h8 __attribute__((ext_vector_type(8)));

#define NROI 2048
#define NCH  256
#define MAPH 256
#define MAPW 256
#define HWSZ (MAPH*MAPW)
#define FDIM 2304
#define MN   (2048*256)

// wbuf (fp16 weights) offsets in halfs
#define O_SH1 0
#define O_SH2 589824
#define O_C1  655360
#define O_C2  720896
#define O_I1  786432
#define O_I2  851968
#define O_R1  917504
#define O_R2  983040

// ---- weight fp32 -> fp16 convert ----
__global__ __launch_bounds__(256) void convert_w_kernel(
    const float* __restrict__ s1, const float* __restrict__ s2,
    const float* __restrict__ c1, const float* __restrict__ c2,
    const float* __restrict__ i1, const float* __restrict__ i2,
    const float* __restrict__ r1, const float* __restrict__ r2,
    __half* __restrict__ wbuf)
{
    const int b = blockIdx.x, t = threadIdx.x;
    const float* src;
    int base;
    if (b < 1152) { src = s1 + (size_t)b*512; base = b*512; }
    else {
        int j  = (b - 1152) >> 7;
        int lb = (b - 1152) & 127;
        switch (j) {
            case 0: src = s2; break; case 1: src = c1; break;
            case 2: src = c2; break; case 3: src = i1; break;
            case 4: src = i2; break; case 5: src = r1; break;
            default: src = r2; break;
        }
        src += (size_t)lb*512;
        base = 589824 + (b - 1152)*512;
    }
    float2 v = *(const float2*)(src + t*2);
    *(__half2*)(wbuf + base + t*2) = __floats2half2_rn(v.x, v.y);
}

// ---- CHW fp32 -> HWC fp16 transpose ----
// v2: lane index maps to x (contiguous) on the global-read side.
// Per wave-instruction: 2 channel-rows x 512B contiguous (vs 64 x 16B
// scattered at 256KB stride in v1). LDS stores swizzled by
// c ^= ((x>>2)&15)<<2 : spreads the stride-4*TP store across 16 banks
// (<=4-way), keeps the h4 read side conflict-free and 8B-aligned.
#define TP 136   // LDS row stride in halves

__global__ __launch_bounds__(256) void transpose_kernel(
    const float* __restrict__ fm, __half* __restrict__ hwc)
{
    __shared__ _Float16 tile[128 * TP];   // [x][c^swz]
    const int tid = threadIdx.x;
    const int x0 = blockIdx.x * 128, c0 = blockIdx.y * 128;
    const int bz = blockIdx.z;
    const int b = bz >> 8, y = bz & 255;

    // read phase: lane = x-quad, 8 channels per pass, 16 passes
    const int xh = tid & 31;              // x quad: x = xh*4 .. xh*4+3
    const int cb = tid >> 5;              // channel sub-index 0..7
    const float* src = fm + (((size_t)b*NCH + c0 + cb)*MAPH + y)*MAPW + x0 + xh*4;
    const int swz = (xh & 15) << 2;       // == ((x>>2)&15)<<2 for all 4 x
    const int xbase = xh * 4;

    #pragma unroll
    for (int p = 0; p < 16; p++) {
        f4v v = *(const f4v*)(src + (size_t)p*8*HWSZ);
        const int c = (cb + p*8) ^ swz;
        tile[(xbase+0)*TP + c] = (_Float16)v[0];
        tile[(xbase+1)*TP + c] = (_Float16)v[1];
        tile[(xbase+2)*TP + c] = (_Float16)v[2];
        tile[(xbase+3)*TP + c] = (_Float16)v[3];
    }
    __syncthreads();

    // write phase: lane = channel quad, h4 vector reads (conflict-free)
    const int cq = tid & 31;              // channel quad
    const int xb = tid >> 5;              // 0..7
    __half* dst = hwc + (((size_t)b*MAPH + y)*MAPW + x0)*NCH + c0 + cq*4;
    #pragma unroll
    for (int it = 0; it < 16; it++) {
        int x = xb + it*8;
        h4 v = *(const h4*)&tile[x*TP + ((cq*4) ^ (((x>>2)&15) << 2))];
        *(h4*)(dst + (size_t)x*NCH) = v;
    }
}

// ---- RoI align from HWC fp16: 2 rois/block, lane = channel quad, waves split pp ----
__global__ __launch_bounds__(256) void roi_hwc_kernel(
    const __half* __restrict__ hwc, const float* __restrict__ boxes,
    const int* __restrict__ bidx, __half* __restrict__ xout)
{
    const int tid  = threadIdx.x;
    const int r    = tid >> 7;         // roi slot
    const int lt   = tid & 127;
    const int wq   = lt >> 6;          // pp parity
    const int lane = lt & 63;          // channel quad index
    const int n    = blockIdx.x * 2 + r;

    __shared__ float sw[2][4][36];
    __shared__ int   soff[2][4][36];
    __shared__ int   sb[2];

    if (lt < 36) {
        float b0 = boxes[n*7+0], b1 = boxes[n*7+1];
        float b4 = boxes[n*7+4], b5 = boxes[n*7+5], b6 = boxes[n*7+6];
        float cx = (b0 + 51.2f) / 0.4f - 0.5f;
        float cy = (b1 + 51.2f) / 0.4f - 0.5f;
        float w  = b5 / 0.4f;
        float h  = b4 / 0.4f;
        float th = -b6;
        float ct = cosf(th), st = sinf(th);
        float binh = h / 3.0f, binw = w / 3.0f;
        int s  = lt;
        int ph = s / 12, pw = (s % 12) / 4, sy = (s % 4) / 2, sx = s & 1;
        float sgy = ((float)sy + 0.5f) * 0.5f;
        float sgx = ((float)sx + 0.5f) * 0.5f;
        float yy  = -h*0.5f + ((float)ph + sgy) * binh;
        float xxl = -w*0.5f + ((float)pw + sgx) * binw;
        float y = yy*ct - xxl*st + cy;
        float x = yy*st + xxl*ct + cx;
        bool valid = (y > -1.0f) && (y < 256.0f) && (x > -1.0f) && (x < 256.0f);
        y = fminf(fmaxf(y, 0.0f), 255.0f);
        x = fminf(fmaxf(x, 0.0f), 255.0f);
        int y0 = (int)floorf(y); if (y0 > 255) y0 = 255;
        int x0 = (int)floorf(x); if (x0 > 255) x0 = 255;
        int y1 = min(y0+1, 255), x1 = min(x0+1, 255);
        float ly = y - (float)y0, lx = x - (float)x0;
        float hy = 1.0f - ly, hx = 1.0f - lx;
        float v = valid ? 0.25f : 0.0f;
        sw[r][0][s] = hy*hx*v; sw[r][1][s] = hy*lx*v;
        sw[r][2][s] = ly*hx*v; sw[r][3][s] = ly*lx*v;
        soff[r][0][s] = (y0*MAPW + x0)*NCH;
        soff[r][1][s] = (y0*MAPW + x1)*NCH;
        soff[r][2][s] = (y1*MAPW + x0)*NCH;
        soff[r][3][s] = (y1*MAPW + x1)*NCH;
    }
    if (lt == 0) sb[r] = bidx[n];
    __syncthreads();

    const __half* base = hwc + (size_t)sb[r]*(HWSZ*NCH) + lane*4;
    __half* xo = xout + (size_t)n*FDIM + lane*4;

    for (int pp = wq; pp < 9; pp += 2) {
        float a0 = 0.f, a1 = 0.f, a2 = 0.f, a3 = 0.f;
        #pragma unroll
        for (int q = 0; q < 4; q++) {
            int s = pp*4 + q;
            #pragma unroll
            for (int cc = 0; cc < 4; cc++) {
                h4 v = *(const h4*)(base + soff[r][cc][s]);
                float wgt = sw[r][cc][s];
                a0 += wgt * (float)v[0];
                a1 += wgt * (float)v[1];
                a2 += wgt * (float)v[2];
                a3 += wgt * (float)v[3];
            }
        }
        h4 o; o[0]=(_Float16)a0; o[1]=(_Float16)a1; o[2]=(_Float16)a2; o[3]=(_Float16)a3;
        *(h4*)(xo + pp*NCH) = o;
    }
}

// ---- fp16 MFMA TN GEMM: C[m][n] = sum_k A[m][k]*W[n][k] ----
struct PtrsH {
    const __half* A[3];
    const __half* W[3];
    void* C[3];
};

__device__ inline h8 ldsH8(const _Float16* p) {
    h4 lo = *(const h4*)p;
    h4 hi = *(const h4*)(p + 4);
    return __builtin_shufflevector(lo, hi, 0,1,2,3,4,5,6,7);
}

template<bool RELU, bool SPLITK, bool OUTH>
__global__ __launch_bounds__(256) void gemm_h_kernel(PtrsH p, int M, int N, int K, int kChunk)
{
    __shared__ _Float16 As[64*40];
    __shared__ _Float16 Ws[64*40];
    const int z = blockIdx.z;
    const _Float16* A; const _Float16* W; void* C;
    int k0, k1;
    if (SPLITK) {
        A = (const _Float16*)p.A[0]; W = (const _Float16*)p.W[0];
        k0 = z * kChunk; k1 = k0 + kChunk;
        C = (char*)p.C[0] + (size_t)z * M * N * 4;
    } else {
        A = (const _Float16*)p.A[z]; W = (const _Float16*)p.W[z]; C = p.C[z];
        k0 = 0; k1 = K;
    }
    const int tid = threadIdx.x;
    const int m0 = blockIdx.x * 64, n0 = blockIdx.y * 64;
    const int srow = tid >> 2, skc = (tid & 3) * 8;
    const _Float16* Ald = A + (size_t)(m0 + srow) * K + k0 + skc;
    const _Float16* Wld = W + (size_t)(n0 + srow) * K + k0 + skc;
    const int wv = tid >> 6, lane = tid & 63;
    const int quad = lane >> 4, mr = lane & 15;

    f4v acc[4] = {};
    h8 aR = *(const h8*)Ald;
    h8 wR = *(const h8*)Wld;

    for (int kt = k0; kt < k1; kt += 32) {
        __syncthreads();
        *(h4*)&As[srow*40 + skc]     = __builtin_shufflevector(aR, aR, 0,1,2,3);
        *(h4*)&As[srow*40 + skc + 4] = __builtin_shufflevector(aR, aR, 4,5,6,7);
        *(h4*)&Ws[srow*40 + skc]     = __builtin_shufflevector(wR, wR, 0,1,2,3);
        *(h4*)&Ws[srow*40 + skc + 4] = __builtin_shufflevector(wR, wR, 4,5,6,7);
        __syncthreads();
        if (kt + 32 < k1) {
            Ald += 32; Wld += 32;
            aR = *(const h8*)Ald;
            wR = *(const h8*)Wld;
        }
        h8 af = ldsH8(&As[(wv*16 + mr)*40 + quad*8]);
        #pragma unroll
        for (int j = 0; j < 4; j++) {
            h8 bf = ldsH8(&Ws[(j*16 + mr)*40 + quad*8]);
            acc[j] = __builtin_amdgcn_mfma_f32_16x16x32_f16(af, bf, acc[j], 0, 0, 0);
        }
    }

    const int orow = m0 + wv*16 + quad*4;
    #pragma unroll
    for (int j = 0; j < 4; j++) {
        int col = n0 + j*16 + mr;
        #pragma unroll
        for (int rr = 0; rr < 4; rr++) {
            float v = acc[j][rr];
            if (RELU) v = fmaxf(v, 0.0f);
            if (OUTH) ((__half*)C)[(size_t)(orow + rr) * N + col] = __float2half(v);
            else      ((float*)C)[(size_t)(orow + rr) * N + col] = v;
        }
    }
}

// ---- split-K reduce + relu -> fp16 ----
__global__ __launch_bounds__(256) void reduce_relu_h_kernel(
    const float* __restrict__ pin, __half* __restrict__ hout)
{
    int i = blockIdx.x * 256 + threadIdx.x;
    const f4v* p4 = (const f4v*)pin;
    f4v a = p4[i];
    a += p4[i + MN/4];
    a += p4[i + 2*(MN/4)];
    a += p4[i + 3*(MN/4)];
    h4 o;
    #pragma unroll
    for (int j = 0; j < 4; j++) o[j] = (_Float16)fmaxf(a[j], 0.0f);
    *(h4*)(hout + (size_t)i*4) = o;
}

// ---- final heads (fp32 GEMV, one wave per roi) ----
__global__ __launch_bounds__(256) void heads_kernel(
    const float* __restrict__ c2, const float* __restrict__ i2, const float* __restrict__ r2,
    const float* __restrict__ wc3, const float* __restrict__ bc3,
    const float* __restrict__ wi3, const float* __restrict__ bi3,
    const float* __restrict__ wr3, const float* __restrict__ br3,
    float* __restrict__ out)
{
    const int lane = threadIdx.x & 63;
    const int wv   = threadIdx.x >> 6;
    const int n    = blockIdx.x * 4 + wv;
    const float* cr = c2 + (size_t)n*256;
    const float* ir = i2 + (size_t)n*256;
    const float* rr = r2 + (size_t)n*256;
    float vc = 0.0f, vi = 0.0f, vr[7] = {};
    #pragma unroll
    for (int j = 0; j < 4; j++) {
        int k = lane + j*64;
        float cv = cr[k], iv = ir[k], rv = rr[k];
        vc += cv * wc3[k];
        vi += iv * wi3[k];
        #pragma unroll
        for (int t = 0; t < 7; t++) vr[t] += rv * wr3[t*256 + k];
    }
    #pragma unroll
    for (int off = 32; off > 0; off >>= 1) {
        vc += __shfl_down(vc, off, 64);
        vi += __shfl_down(vi, off, 64);
        #pragma unroll
        for (int t = 0; t < 7; t++) vr[t] += __shfl_down(vr[t], off, 64);
    }
    if (lane == 0) {
        out[n]        = vc + bc3[0];
        out[2048 + n] = vi + bi3[0];
        #pragma unroll
        for (int t = 0; t < 7; t++) out[4096 + n*7 + t] = vr[t] + br3[t];
    }
}

extern "C" void kernel_launch(void* const* d_in, const int* in_sizes, int n_in,
                              void* d_out, int out_size, void* d_ws, size_t ws_size,
                              hipStream_t stream)
{
    const float* fm    = (const float*)d_in[0];
    const float* boxes = (const float*)d_in[1];
    const int*   bidx  = (const int*)d_in[2];
    const float* w_sh1 = (const float*)d_in[3];
    const float* w_sh2 = (const float*)d_in[4];
    const float* w_c1  = (const float*)d_in[5];
    const float* w_c2  = (const float*)d_in[6];
    const float* w_c3  = (const float*)d_in[7];
    const float* b_c3  = (const float*)d_in[8];
    const float* w_i1  = (const float*)d_in[9];
    const float* w_i2  = (const float*)d_in[10];
    const float* w_i3  = (const float*)d_in[11];
    const float* b_i3  = (const float*)d_in[12];
    const float* w_r1  = (const float*)d_in[13];
    const float* w_r2  = (const float*)d_in[14];
    const float* w_r3  = (const float*)d_in[15];
    const float* b_r3  = (const float*)d_in[16];
    float* out = (float*)d_out;

    // workspace layout (bytes)
    char* base = (char*)d_ws;
    __half* hwc  = (__half*)base;                                   // 128 MB
    __half* xh   = (__half*)(base + (size_t)4*NCH*HWSZ*2);          // 9 MB
    __half* h1h  = (__half*)((char*)xh + (size_t)NROI*FDIM*2);      // 1 MB
    __half* shh  = (__half*)((char*)h1h + (size_t)MN*2);            // 1 MB
    __half* b1c  = (__half*)((char*)shh + (size_t)MN*2);            // 3 MB
    __half* b1i  = b1c + MN;
    __half* b1r  = b1i + MN;
    float*  b2c  = (float*)((char*)b1c + (size_t)3*MN*2);           // 6 MB
    float*  b2i  = b2c + MN;
    float*  b2r  = b2i + MN;
    float*  part = (float*)((char*)b2c + (size_t)3*MN*4);           // 8 MB
    __half* wbuf = (__half*)((char*)part + (size_t)4*MN*4);         // 2 MB

    convert_w_kernel<<<2048, 256, 0, stream>>>(w_sh1, w_sh2, w_c1, w_c2,
                                               w_i1, w_i2, w_r1, w_r2, wbuf);
    transpose_kernel<<<dim3(2, 2, 4*MAPH), 256, 0, stream>>>(fm, hwc);
    roi_hwc_kernel<<<NROI/2, 256, 0, stream>>>(hwc, boxes, bidx, xh);

    PtrsH g1;
    g1.A[0]=g1.A[1]=g1.A[2]=xh;
    g1.W[0]=g1.W[1]=g1.W[2]=wbuf + O_SH1;
    g1.C[0]=g1.C[1]=g1.C[2]=part;
    gemm_h_kernel<false,true,false><<<dim3(32,4,4), 256, 0, stream>>>(g1, 2048, 256, 2304, 576);

    reduce_relu_h_kernel<<<MN/4/256, 256, 0, stream>>>(part, h1h);

    PtrsH g2;
    g2.A[0]=g2.A[1]=g2.A[2]=h1h;
    g2.W[0]=g2.W[1]=g2.W[2]=wbuf + O_SH2;
    g2.C[0]=g2.C[1]=g2.C[2]=shh;
    gemm_h_kernel<true,false,true><<<dim3(32,4,1), 256, 0, stream>>>(g2, 2048, 256, 256, 0);

    PtrsH g3;
    g3.A[0]=g3.A[1]=g3.A[2]=shh;
    g3.W[0]=wbuf + O_C1; g3.W[1]=wbuf + O_I1; g3.W[2]=wbuf + O_R1;
    g3.C[0]=b1c; g3.C[1]=b1i; g3.C[2]=b1r;
    gemm_h_kernel<true,false,true><<<dim3(32,4,3), 256, 0, stream>>>(g3, 2048, 256, 256, 0);

    PtrsH g4;
    g4.A[0]=b1c; g4.A[1]=b1i; g4.A[2]=b1r;
    g4.W[0]=wbuf + O_C2; g4.W[1]=wbuf + O_I2; g4.W[2]=wbuf + O_R2;
    g4.C[0]=b2c; g4.C[1]=b2i; g4.C[2]=b2r;
    gemm_h_kernel<true,false,false><<<dim3(32,4,3), 256, 0, stream>>>(g4, 2048, 256, 256, 0);

    heads_kernel<<<NROI/4, 256, 0, stream>>>(b2c, b2i, b2r,
                                             w_c3, b_c3, w_i3, b_i3, w_r3, b_r3, out);
}